// Round 4
// baseline (11470.152 us; speedup 1.0000x reference)
//
#include <hip/hip_runtime.h>
#include <hip/hip_bf16.h>

#define B_   64
#define S_   128
#define T_   64
#define H_   1024
#define E_   512
#define V_   16000
#define ENC_ 2048
#define XDIM_ (E_ + ENC_)   // 2560
#define G3_  (3 * H_)       // 3072
#define QGH_ (4 * H_)       // 4096 (q | gh)

typedef __attribute__((ext_vector_type(8))) short bf16x8;
typedef __attribute__((ext_vector_type(8))) unsigned short u16x8;
typedef __attribute__((ext_vector_type(4))) float f32x4;

__device__ __forceinline__ ushort f2bf(float x) {
    __hip_bfloat16 h = __float2bfloat16(x);
    return *reinterpret_cast<ushort*>(&h);
}
__device__ __forceinline__ float bf2f(ushort u) {
    return __uint_as_float((unsigned)u << 16);
}
__device__ __forceinline__ float sigmoidf_(float x) {
    return 1.f / (1.f + expf(-x));
}

// async global->LDS, 16B per lane
__device__ __forceinline__ void gload_lds16(const ushort* g, ushort* l) {
    __builtin_amdgcn_global_load_lds(
        (const __attribute__((address_space(1))) unsigned int*)g,
        (__attribute__((address_space(3))) unsigned int*)l, 16, 0, 0);
}

// ---------------------------------------------------------------------------
// Grid barrier (sense-reversing, agent scope). bar[0]=counter, bar[1]=gen.
// Release: __threadfence (L2 writeback) before arrival; counter reset is
// release-ordered before the gen bump; waiters spin RELAXED (no cache inv
// per poll) then acquire via __threadfence once after wakeup.
// ---------------------------------------------------------------------------
__device__ __forceinline__ void grid_barrier(unsigned* bar, unsigned nb) {
    __syncthreads();
    if (threadIdx.x == 0) {
        __threadfence();   // release: publish this block's writes
        unsigned g = __hip_atomic_load(&bar[1], __ATOMIC_RELAXED, __HIP_MEMORY_SCOPE_AGENT);
        unsigned a = __hip_atomic_fetch_add(&bar[0], 1u, __ATOMIC_RELAXED, __HIP_MEMORY_SCOPE_AGENT);
        if (a == nb - 1u) {
            __hip_atomic_store(&bar[0], 0u, __ATOMIC_RELAXED, __HIP_MEMORY_SCOPE_AGENT);
            // RELEASE orders the counter reset before the gen bump
            __hip_atomic_store(&bar[1], g + 1u, __ATOMIC_RELEASE, __HIP_MEMORY_SCOPE_AGENT);
        } else {
            while (__hip_atomic_load(&bar[1], __ATOMIC_RELAXED, __HIP_MEMORY_SCOPE_AGENT) == g)
                __builtin_amdgcn_s_sleep(2);
        }
        __threadfence();   // acquire: invalidate stale L1/L2 lines
    }
    __syncthreads();
}

// ---------------------------------------------------------------------------
// m97-structure GEMM: C[M,N] = A[M,K] @ W[N,K]^T + bias[N]
// 128x128 tile, BK=32, 256 threads (4 waves, 64x64 quadrants each).
// ---------------------------------------------------------------------------
__global__ __launch_bounds__(256) void gemm128_bf16(
    const ushort* __restrict__ A, int lda,
    const ushort* __restrict__ W, int ldw,
    const float* __restrict__ bias,
    float* __restrict__ Cf, ushort* __restrict__ Cb, int ldc,
    int K)
{
    const int bn0 = blockIdx.x * 128;
    const int bm0 = blockIdx.y * 128;
    const int tid = threadIdx.x;
    const int wv  = tid >> 6;
    const int lane = tid & 63;

    __shared__ ushort As[128 * 32];
    __shared__ ushort Bs[128 * 32];

    const int srow = tid >> 2;
    const int scol = (tid & 3) * 8;

    const ushort* gA0 = A + (size_t)(bm0 + srow) * lda + scol;
    const ushort* gA1 = gA0 + (size_t)64 * lda;
    const ushort* gB0 = W + (size_t)(bn0 + srow) * ldw + scol;
    const ushort* gB1 = gB0 + (size_t)64 * ldw;

    ushort* lA0 = &As[tid * 8];
    ushort* lA1 = &As[2048 + tid * 8];
    ushort* lB0 = &Bs[tid * 8];
    ushort* lB1 = &Bs[2048 + tid * 8];

    const int wr0 = (wv >> 1) * 64;
    const int wc0 = (wv & 1) * 64;
    const int frow = lane & 15;
    const int fk   = (lane >> 4) * 8;

    f32x4 acc[4][4];
#pragma unroll
    for (int i = 0; i < 4; ++i)
#pragma unroll
        for (int j = 0; j < 4; ++j) acc[i][j] = (f32x4){0.f, 0.f, 0.f, 0.f};

    for (int k0 = 0; k0 < K; k0 += 32) {
        gload_lds16(gA0 + k0, lA0);
        gload_lds16(gA1 + k0, lA1);
        gload_lds16(gB0 + k0, lB0);
        gload_lds16(gB1 + k0, lB1);
        __syncthreads();

        bf16x8 af[4], bf[4];
#pragma unroll
        for (int rb = 0; rb < 4; ++rb)
            af[rb] = *reinterpret_cast<const bf16x8*>(&As[(wr0 + rb * 16 + frow) * 32 + fk]);
#pragma unroll
        for (int cb = 0; cb < 4; ++cb)
            bf[cb] = *reinterpret_cast<const bf16x8*>(&Bs[(wc0 + cb * 16 + frow) * 32 + fk]);
#pragma unroll
        for (int rb = 0; rb < 4; ++rb)
#pragma unroll
            for (int cb = 0; cb < 4; ++cb)
                acc[rb][cb] = __builtin_amdgcn_mfma_f32_16x16x32_bf16(af[rb], bf[cb], acc[rb][cb], 0, 0, 0);
        __syncthreads();
    }

    const int quad = lane >> 4;
#pragma unroll
    for (int cb = 0; cb < 4; ++cb) {
        const int col = bn0 + wc0 + cb * 16 + frow;
        const float bv = bias ? bias[col] : 0.f;
#pragma unroll
        for (int rb = 0; rb < 4; ++rb) {
            const int row0 = bm0 + wr0 + rb * 16 + quad * 4;
            f32x4 a = acc[rb][cb];
#pragma unroll
            for (int r = 0; r < 4; ++r) {
                const float val = a[r] + bv;
                if (Cb) Cb[(size_t)(row0 + r) * ldc + col] = f2bf(val);
                else    Cf[(size_t)(row0 + r) * ldc + col] = val;
            }
        }
    }
}

// ---------------------------------------------------------------------------
// Packs
// ---------------------------------------------------------------------------
__global__ __launch_bounds__(256) void pack_bf16(
    const float* __restrict__ src, int src_ld, int c0, int ncols,
    ushort* __restrict__ dst, size_t total)
{
    size_t i = (size_t)blockIdx.x * 256 + threadIdx.x;
    const size_t stride = (size_t)gridDim.x * 256;
    for (; i < total; i += stride) {
        size_t r = i / (size_t)ncols;
        int c = (int)(i - r * (size_t)ncols);
        dst[i] = f2bf(src[r * (size_t)src_ld + c0 + c]);
    }
}

__global__ __launch_bounds__(256) void gather_emb(
    const int* __restrict__ target, const float* __restrict__ emb,
    ushort* __restrict__ dst)
{
    const int row = blockIdx.x;          // b*T + t
    const int b = row >> 6;
    const int t = row & 63;
    const int tok = (t == 0) ? 1 : target[b * T_ + t - 1];
    const float* e = emb + (size_t)tok * E_;
    ushort* d = dst + (size_t)row * E_;
    for (int c = threadIdx.x; c < E_; c += 256) d[c] = f2bf(e[c]);
}

__global__ __launch_bounds__(256) void pack_bhq(
    const float* __restrict__ ba, const float* __restrict__ bhh,
    float* __restrict__ dst)
{
    const int j = blockIdx.x * 256 + threadIdx.x;
    if (j < H_) dst[j] = ba[j];
    else if (j < QGH_) dst[j] = bhh[j - H_];
}

__global__ void barinit(unsigned* bar) {
    if (threadIdx.x < 2) bar[threadIdx.x] = 0u;
}

// ---------------------------------------------------------------------------
// Persistent decoder: the whole T=64 recurrence in one kernel.
// Grid: 256 blocks x 512 threads. 4 grid barriers per step.
//   P1: qgh = h_prev @ [Wa_q;W_hh]^T + [ba;b_hh]  (block = 16-col slice)
//   P2: scores (block = b x s-slice32)
//   P3: softmax + ctx (block = b x e-slice512)
//   P4: gi (3 gate tiles, same 16-col offset) + GRU (block = jslice x bquarter)
// ---------------------------------------------------------------------------
__global__ __launch_bounds__(512) void decoder_persist(
    const ushort* __restrict__ encp,   // (B,S,H) bf16
    const ushort* __restrict__ enc,    // (B,S,ENC) bf16
    const ushort* __restrict__ ench,   // (B,H) bf16 h0
    const float*  __restrict__ ench_f, // (B,H) fp32 h0
    const ushort* __restrict__ Whq,    // (4096,1024) bf16
    const ushort* __restrict__ Wie,    // (3072,2048) bf16
    const float*  __restrict__ bhq,    // (4096)
    const float*  __restrict__ vvec,   // (1024)
    const float*  __restrict__ giemb,  // (B*T,3H) fp32 (incl b_ih)
    float* __restrict__ qgh,           // (B,4096)
    float* __restrict__ scores,        // (B,S)
    ushort* __restrict__ ctx,          // (B,ENC) bf16
    float* __restrict__ hall_f,        // (B,T,H)
    ushort* __restrict__ hall_b,       // (B,T,H)
    unsigned* __restrict__ bar)
{
    const int blk = blockIdx.x;
    const int tid = threadIdx.x;
    const int wv = tid >> 6;
    const int lane = tid & 63;
    const int frow = lane & 15;
    const int fk = (lane >> 4) * 8;
    const unsigned nb = gridDim.x;

    __shared__ __align__(16) char smem_raw[28672];

    for (int t = 0; t < T_; ++t) {
        const ushort* hb = t ? (hall_b + (size_t)(t - 1) * H_) : ench;
        const float*  hf = t ? (hall_f + (size_t)(t - 1) * H_) : ench_f;
        const int ldh = t ? (T_ * H_) : H_;

        // ---------------- P1: qgh ----------------
        {
            f32x4 (*red)[64] = reinterpret_cast<f32x4(*)[64]>(smem_raw);
            const int n0 = blk * 16;
            const int mt = wv & 3;      // m-tile (16 rows)
            const int kh = wv >> 2;     // K-half
            const ushort* Arow = hb + (size_t)(mt * 16 + frow) * ldh + kh * 512 + fk;
            const ushort* Brow = Whq + (size_t)(n0 + frow) * H_ + kh * 512 + fk;
            f32x4 acc = (f32x4){0.f, 0.f, 0.f, 0.f};
#pragma unroll
            for (int c = 0; c < 16; ++c) {
                bf16x8 a = *reinterpret_cast<const bf16x8*>(Arow + c * 32);
                bf16x8 b = *reinterpret_cast<const bf16x8*>(Brow + c * 32);
                acc = __builtin_amdgcn_mfma_f32_16x16x32_bf16(a, b, acc, 0, 0, 0);
            }
            red[wv][lane] = acc;
            __syncthreads();
            if (wv < 4) {
                f32x4 s = red[wv][lane] + red[wv + 4][lane];
                const int col = n0 + frow;
                const float bv = bhq[col];
                const int row0 = wv * 16 + (lane >> 4) * 4;
#pragma unroll
                for (int r = 0; r < 4; ++r)
                    qgh[(size_t)(row0 + r) * QGH_ + col] = s[r] + bv;
            }
        }
        grid_barrier(bar, nb);

        // ---------------- P2: scores ----------------
        {
            float* qs = reinterpret_cast<float*>(smem_raw);
            float* vs = qs + H_;
            const int b = blk >> 2;
            const int s0 = (blk & 3) * 32;
            qs[tid]       = qgh[(size_t)b * QGH_ + tid];
            qs[tid + 512] = qgh[(size_t)b * QGH_ + tid + 512];
            vs[tid]       = vvec[tid];
            vs[tid + 512] = vvec[tid + 512];
            __syncthreads();
            const int h0 = lane * 16;
#pragma unroll
            for (int i = 0; i < 4; ++i) {
                const int s = s0 + wv * 4 + i;
                const ushort* ep = encp + ((size_t)b * S_ + s) * H_ + h0;
                float pacc = 0.f;
#pragma unroll
                for (int v8 = 0; v8 < 2; ++v8) {
                    u16x8 ev = *reinterpret_cast<const u16x8*>(ep + v8 * 8);
#pragma unroll
                    for (int j = 0; j < 8; ++j) {
                        const int h = h0 + v8 * 8 + j;
                        pacc += vs[h] * tanhf(qs[h] + bf2f(ev[j]));
                    }
                }
#pragma unroll
                for (int off = 32; off; off >>= 1) pacc += __shfl_xor(pacc, off);
                if (lane == 0) scores[b * S_ + s] = pacc;
            }
        }
        grid_barrier(bar, nb);

        // ---------------- P3: softmax + ctx ----------------
        {
            float* al = reinterpret_cast<float*>(smem_raw);
            const int b = blk >> 2;
            const int e0 = (blk & 3) * 512;
            if (tid < 64) {
                float a0 = scores[b * S_ + tid];
                float a1 = scores[b * S_ + tid + 64];
                float m = fmaxf(a0, a1);
#pragma unroll
                for (int off = 32; off; off >>= 1) m = fmaxf(m, __shfl_xor(m, off));
                float e0v = expf(a0 - m), e1v = expf(a1 - m);
                float ssum = e0v + e1v;
#pragma unroll
                for (int off = 32; off; off >>= 1) ssum += __shfl_xor(ssum, off);
                const float inv = 1.f / ssum;
                al[tid] = e0v * inv;
                al[tid + 64] = e1v * inv;
            }
            __syncthreads();
            const int e = e0 + tid;
            const ushort* eb = enc + (size_t)b * S_ * ENC_ + e;
            float acc = 0.f;
#pragma unroll 8
            for (int s = 0; s < S_; ++s)
                acc = fmaf(al[s], bf2f(eb[(size_t)s * ENC_]), acc);
            ctx[(size_t)b * ENC_ + e] = f2bf(acc);
        }
        grid_barrier(bar, nb);

        // ---------------- P4: gi (3 gates, one 16-col offset) + GRU ----------------
        {
            f32x4 (*redp)[3][64] = reinterpret_cast<f32x4(*)[3][64]>(smem_raw);
            float (*gt)[16][16] = reinterpret_cast<float(*)[16][16]>(smem_raw + 24576);
            const int jt = blk >> 2;     // j-slice 0..63
            const int mq = blk & 3;      // b-quarter
            const int b0 = mq * 16;
            const int kc = wv * 256;     // K-chunk per wave

            const ushort* Arow = ctx + (size_t)(b0 + frow) * ENC_ + kc + fk;
            const ushort* Brow = Wie + (size_t)(jt * 16 + frow) * ENC_ + kc + fk;
            f32x4 a0 = (f32x4){0.f, 0.f, 0.f, 0.f};
            f32x4 a1 = a0, a2 = a0;
#pragma unroll
            for (int c = 0; c < 8; ++c) {
                bf16x8 av = *reinterpret_cast<const bf16x8*>(Arow + c * 32);
                bf16x8 br = *reinterpret_cast<const bf16x8*>(Brow + c * 32);
                bf16x8 bz = *reinterpret_cast<const bf16x8*>(Brow + (size_t)1024 * ENC_ + c * 32);
                bf16x8 bn = *reinterpret_cast<const bf16x8*>(Brow + (size_t)2048 * ENC_ + c * 32);
                a0 = __builtin_amdgcn_mfma_f32_16x16x32_bf16(av, br, a0, 0, 0, 0);
                a1 = __builtin_amdgcn_mfma_f32_16x16x32_bf16(av, bz, a1, 0, 0, 0);
                a2 = __builtin_amdgcn_mfma_f32_16x16x32_bf16(av, bn, a2, 0, 0, 0);
            }
            redp[wv][0][lane] = a0;
            redp[wv][1][lane] = a1;
            redp[wv][2][lane] = a2;
            __syncthreads();
            if (wv < 3) {
                f32x4 s = redp[0][wv][lane];
#pragma unroll
                for (int w = 1; w < 8; ++w) s += redp[w][wv][lane];
                const int row0 = (lane >> 4) * 4;
#pragma unroll
                for (int r = 0; r < 4; ++r) gt[wv][row0 + r][frow] = s[r];
            }
            __syncthreads();
            if (tid < 256) {
                const int bl = tid >> 4, jl = tid & 15;
                const int b = b0 + bl;
                const int j = jt * 16 + jl;
                const size_t gr = (size_t)(b * T_ + t) * G3_;
                const float ir  = gt[0][bl][jl] + giemb[gr + j];
                const float iz  = gt[1][bl][jl] + giemb[gr + H_ + j];
                const float in_ = gt[2][bl][jl] + giemb[gr + 2 * H_ + j];
                const float* ghp = qgh + (size_t)b * QGH_ + H_;
                const float r = sigmoidf_(ir + ghp[j]);
                const float z = sigmoidf_(iz + ghp[H_ + j]);
                const float n = tanhf(in_ + r * ghp[2 * H_ + j]);
                const float hnew = (1.f - z) * n + z * hf[(size_t)b * ldh + j];
                const size_t ho = (size_t)b * (T_ * H_) + (size_t)t * H_ + j;
                hall_f[ho] = hnew;
                hall_b[ho] = f2bf(hnew);
            }
        }
        grid_barrier(bar, nb);
    }
}

// ---------------------------------------------------------------------------
static inline int pgrid(size_t total) {
    size_t nb = (total + 255) / 256;
    if (nb > 4096) nb = 4096;
    return (int)nb;
}

extern "C" void kernel_launch(void* const* d_in, const int* in_sizes, int n_in,
                              void* d_out, int out_size, void* d_ws, size_t ws_size,
                              hipStream_t stream) {
    const float* enc    = (const float*)d_in[0];
    const float* enc_h  = (const float*)d_in[1];
    const int*   target = (const int*)  d_in[2];
    const float* emb    = (const float*)d_in[3];
    const float* Wa     = (const float*)d_in[4];
    const float* ba     = (const float*)d_in[5];
    const float* vvec   = (const float*)d_in[6];
    const float* W_ih   = (const float*)d_in[7];
    const float* b_ih   = (const float*)d_in[8];
    const float* W_hh   = (const float*)d_in[9];
    const float* b_hh   = (const float*)d_in[10];
    const float* Wo     = (const float*)d_in[11];
    const float* bo     = (const float*)d_in[12];
    float* out = (float*)d_out;

    char* p = (char*)d_ws;
    auto alloc_u16 = [&](size_t n) { ushort* r = (ushort*)p; p += n * 2; return r; };
    auto alloc_f32 = [&](size_t n) { float* r = (float*)p; p += n * 4; return r; };

    ushort* enc_bf  = alloc_u16((size_t)B_ * S_ * ENC_);
    ushort* encp_bf = alloc_u16((size_t)B_ * S_ * H_);
    ushort* Wo_bf   = alloc_u16((size_t)V_ * H_);
    ushort* Wae_bf  = alloc_u16((size_t)H_ * ENC_);
    ushort* Whq_bf  = alloc_u16((size_t)QGH_ * H_);
    ushort* Wie_bf  = alloc_u16((size_t)G3_ * ENC_);
    ushort* Wiee_bf = alloc_u16((size_t)G3_ * E_);
    ushort* ench_bf = alloc_u16((size_t)B_ * H_);
    ushort* Xemb_bf = alloc_u16((size_t)B_ * T_ * E_);
    ushort* hall_bf = alloc_u16((size_t)B_ * T_ * H_);
    ushort* ctx_bf  = alloc_u16((size_t)B_ * ENC_);
    float* hall_f   = alloc_f32((size_t)B_ * T_ * H_);
    float* giemb    = alloc_f32((size_t)B_ * T_ * G3_);
    float* qgh      = alloc_f32((size_t)B_ * QGH_);
    float* bhq      = alloc_f32((size_t)QGH_);
    float* scores   = alloc_f32((size_t)B_ * S_);
    unsigned* bar   = (unsigned*)alloc_f32(64);   // barrier state (256B)

    const int LDW = H_ + ENC_;   // 3072

    // ---- packs ----
    pack_bf16<<<pgrid((size_t)B_*S_*ENC_), 256, 0, stream>>>(enc, ENC_, 0, ENC_, enc_bf, (size_t)B_*S_*ENC_);
    pack_bf16<<<pgrid((size_t)V_*H_), 256, 0, stream>>>(Wo, H_, 0, H_, Wo_bf, (size_t)V_*H_);
    pack_bf16<<<pgrid((size_t)H_*ENC_), 256, 0, stream>>>(Wa, LDW, H_, ENC_, Wae_bf, (size_t)H_*ENC_);
    pack_bf16<<<pgrid((size_t)H_*H_), 256, 0, stream>>>(Wa, LDW, 0, H_, Whq_bf, (size_t)H_*H_);
    pack_bf16<<<pgrid((size_t)G3_*H_), 256, 0, stream>>>(W_hh, H_, 0, H_, Whq_bf + (size_t)H_*H_, (size_t)G3_*H_);
    pack_bf16<<<pgrid((size_t)G3_*ENC_), 256, 0, stream>>>(W_ih, XDIM_, E_, ENC_, Wie_bf, (size_t)G3_*ENC_);
    pack_bf16<<<pgrid((size_t)G3_*E_), 256, 0, stream>>>(W_ih, XDIM_, 0, E_, Wiee_bf, (size_t)G3_*E_);
    pack_bf16<<<pgrid((size_t)B_*H_), 256, 0, stream>>>(enc_h, H_, 0, H_, ench_bf, (size_t)B_*H_);
    gather_emb<<<B_*T_, 256, 0, stream>>>(target, emb, Xemb_bf);
    pack_bhq<<<QGH_/256, 256, 0, stream>>>(ba, b_hh, bhq);
    barinit<<<1, 64, 0, stream>>>(bar);

    // ---- big parallel GEMMs ----
    gemm128_bf16<<<dim3(H_/128, (B_*S_)/128), 256, 0, stream>>>(
        enc_bf, ENC_, Wae_bf, ENC_, nullptr, nullptr, encp_bf, H_, ENC_);
    gemm128_bf16<<<dim3(G3_/128, (B_*T_)/128), 256, 0, stream>>>(
        Xemb_bf, E_, Wiee_bf, E_, b_ih, giemb, nullptr, G3_, E_);

    // ---- persistent recurrence ----
    decoder_persist<<<256, 512, 0, stream>>>(
        encp_bf, enc_bf, ench_bf, enc_h, Whq_bf, Wie_bf, bhq, vvec, giemb,
        qgh, scores, ctx_bf, hall_f, hall_bf, bar);

    // ---- output projection ----
    gemm128_bf16<<<dim3(V_/128, (B_*T_)/128), 256, 0, stream>>>(
        hall_bf, H_, Wo_bf, H_, bo, out, nullptr, V_, H_);
}

// Round 5
// 7493.490 us; speedup vs baseline: 1.5307x; 1.5307x over previous
//
#include <hip/hip_runtime.h>
#include <hip/hip_bf16.h>

#define B_   64
#define S_   128
#define T_   64
#define H_   1024
#define E_   512
#define V_   16000
#define ENC_ 2048
#define XDIM_ (E_ + ENC_)   // 2560
#define G3_  (3 * H_)       // 3072
#define QGH_ (4 * H_)       // 4096 (q | gh)
#define NB_  256            // persistent grid size

typedef __attribute__((ext_vector_type(8))) short bf16x8;
typedef __attribute__((ext_vector_type(8))) unsigned short u16x8;
typedef __attribute__((ext_vector_type(4))) float f32x4;

__device__ __forceinline__ ushort f2bf(float x) {
    __hip_bfloat16 h = __float2bfloat16(x);
    return *reinterpret_cast<ushort*>(&h);
}
__device__ __forceinline__ float bf2f(ushort u) {
    return __uint_as_float((unsigned)u << 16);
}
__device__ __forceinline__ float sigmoidf_(float x) {
    return 1.f / (1.f + expf(-x));
}

// async global->LDS, 16B per lane
__device__ __forceinline__ void gload_lds16(const ushort* g, ushort* l) {
    __builtin_amdgcn_global_load_lds(
        (const __attribute__((address_space(1))) unsigned int*)g,
        (__attribute__((address_space(3))) unsigned int*)l, 16, 0, 0);
}

// ---------------------------------------------------------------------------
// Contention-free grid barrier. flags[i*32] (128B-strided lines) hold the
// last generation block i arrived at; go[0] holds the released generation.
// Arrival = ONE release store per block (no RMW serialization). Block 0's
// threads 1..255 poll the 255 flags in parallel, then thread 0 fences and
// release-stores go = gen. gen is monotonically increasing (no ABA).
// ---------------------------------------------------------------------------
__device__ __forceinline__ void gbar(unsigned* flags, unsigned* go, unsigned gen) {
    __syncthreads();
    const int tid = threadIdx.x;
    if (blockIdx.x == 0) {
        if (tid >= 1 && tid < NB_) {
            while (__hip_atomic_load(&flags[tid * 32], __ATOMIC_RELAXED,
                                     __HIP_MEMORY_SCOPE_AGENT) < gen)
                __builtin_amdgcn_s_sleep(1);
        }
        __syncthreads();   // all 255 flags observed
        if (tid == 0) {
            __threadfence();   // wb+inv: publish block0 data, order flag reads
            __hip_atomic_store(go, gen, __ATOMIC_RELEASE, __HIP_MEMORY_SCOPE_AGENT);
        }
    } else {
        if (tid == 0) {
            // release store publishes this block's phase writes
            __hip_atomic_store(&flags[blockIdx.x * 32], gen, __ATOMIC_RELEASE,
                               __HIP_MEMORY_SCOPE_AGENT);
            while (__hip_atomic_load(go, __ATOMIC_RELAXED,
                                     __HIP_MEMORY_SCOPE_AGENT) < gen)
                __builtin_amdgcn_s_sleep(1);
            __threadfence();   // acquire: invalidate stale L1/L2 lines
        }
    }
    __syncthreads();
}

// ---------------------------------------------------------------------------
// m97-structure GEMM: C[M,N] = A[M,K] @ W[N,K]^T + bias[N]
// ---------------------------------------------------------------------------
__global__ __launch_bounds__(256) void gemm128_bf16(
    const ushort* __restrict__ A, int lda,
    const ushort* __restrict__ W, int ldw,
    const float* __restrict__ bias,
    float* __restrict__ Cf, ushort* __restrict__ Cb, int ldc,
    int K)
{
    const int bn0 = blockIdx.x * 128;
    const int bm0 = blockIdx.y * 128;
    const int tid = threadIdx.x;
    const int wv  = tid >> 6;
    const int lane = tid & 63;

    __shared__ ushort As[128 * 32];
    __shared__ ushort Bs[128 * 32];

    const int srow = tid >> 2;
    const int scol = (tid & 3) * 8;

    const ushort* gA0 = A + (size_t)(bm0 + srow) * lda + scol;
    const ushort* gA1 = gA0 + (size_t)64 * lda;
    const ushort* gB0 = W + (size_t)(bn0 + srow) * ldw + scol;
    const ushort* gB1 = gB0 + (size_t)64 * ldw;

    ushort* lA0 = &As[tid * 8];
    ushort* lA1 = &As[2048 + tid * 8];
    ushort* lB0 = &Bs[tid * 8];
    ushort* lB1 = &Bs[2048 + tid * 8];

    const int wr0 = (wv >> 1) * 64;
    const int wc0 = (wv & 1) * 64;
    const int frow = lane & 15;
    const int fk   = (lane >> 4) * 8;

    f32x4 acc[4][4];
#pragma unroll
    for (int i = 0; i < 4; ++i)
#pragma unroll
        for (int j = 0; j < 4; ++j) acc[i][j] = (f32x4){0.f, 0.f, 0.f, 0.f};

    for (int k0 = 0; k0 < K; k0 += 32) {
        gload_lds16(gA0 + k0, lA0);
        gload_lds16(gA1 + k0, lA1);
        gload_lds16(gB0 + k0, lB0);
        gload_lds16(gB1 + k0, lB1);
        __syncthreads();

        bf16x8 af[4], bf[4];
#pragma unroll
        for (int rb = 0; rb < 4; ++rb)
            af[rb] = *reinterpret_cast<const bf16x8*>(&As[(wr0 + rb * 16 + frow) * 32 + fk]);
#pragma unroll
        for (int cb = 0; cb < 4; ++cb)
            bf[cb] = *reinterpret_cast<const bf16x8*>(&Bs[(wc0 + cb * 16 + frow) * 32 + fk]);
#pragma unroll
        for (int rb = 0; rb < 4; ++rb)
#pragma unroll
            for (int cb = 0; cb < 4; ++cb)
                acc[rb][cb] = __builtin_amdgcn_mfma_f32_16x16x32_bf16(af[rb], bf[cb], acc[rb][cb], 0, 0, 0);
        __syncthreads();
    }

    const int quad = lane >> 4;
#pragma unroll
    for (int cb = 0; cb < 4; ++cb) {
        const int col = bn0 + wc0 + cb * 16 + frow;
        const float bv = bias ? bias[col] : 0.f;
#pragma unroll
        for (int rb = 0; rb < 4; ++rb) {
            const int row0 = bm0 + wr0 + rb * 16 + quad * 4;
            f32x4 a = acc[rb][cb];
#pragma unroll
            for (int r = 0; r < 4; ++r) {
                const float val = a[r] + bv;
                if (Cb) Cb[(size_t)(row0 + r) * ldc + col] = f2bf(val);
                else    Cf[(size_t)(row0 + r) * ldc + col] = val;
            }
        }
    }
}

// ---------------------------------------------------------------------------
// Packs
// ---------------------------------------------------------------------------
__global__ __launch_bounds__(256) void pack_bf16(
    const float* __restrict__ src, int src_ld, int c0, int ncols,
    ushort* __restrict__ dst, size_t total)
{
    size_t i = (size_t)blockIdx.x * 256 + threadIdx.x;
    const size_t stride = (size_t)gridDim.x * 256;
    for (; i < total; i += stride) {
        size_t r = i / (size_t)ncols;
        int c = (int)(i - r * (size_t)ncols);
        dst[i] = f2bf(src[r * (size_t)src_ld + c0 + c]);
    }
}

__global__ __launch_bounds__(256) void gather_emb(
    const int* __restrict__ target, const float* __restrict__ emb,
    ushort* __restrict__ dst)
{
    const int row = blockIdx.x;          // b*T + t
    const int b = row >> 6;
    const int t = row & 63;
    const int tok = (t == 0) ? 1 : target[b * T_ + t - 1];
    const float* e = emb + (size_t)tok * E_;
    ushort* d = dst + (size_t)row * E_;
    for (int c = threadIdx.x; c < E_; c += 256) d[c] = f2bf(e[c]);
}

__global__ __launch_bounds__(256) void pack_bhq(
    const float* __restrict__ ba, const float* __restrict__ bhh,
    float* __restrict__ dst)
{
    const int j = blockIdx.x * 256 + threadIdx.x;
    if (j < H_) dst[j] = ba[j];
    else if (j < QGH_) dst[j] = bhh[j - H_];
}

// zero flags (256*32) + go (1) = 8193 -> zero 8448 for slack
__global__ __launch_bounds__(256) void barinit(unsigned* f) {
    const int i = blockIdx.x * 256 + threadIdx.x;
    if (i < 8448) f[i] = 0u;
}

// ---------------------------------------------------------------------------
// Persistent decoder: whole T=64 recurrence. 256 blocks x 512 threads,
// 4 flag-barriers per step.
// ---------------------------------------------------------------------------
__global__ __launch_bounds__(512) void decoder_persist(
    const ushort* __restrict__ encp,   // (B,S,H) bf16
    const ushort* __restrict__ enc,    // (B,S,ENC) bf16
    const ushort* __restrict__ ench,   // (B,H) bf16 h0
    const float*  __restrict__ ench_f, // (B,H) fp32 h0
    const ushort* __restrict__ Whq,    // (4096,1024) bf16
    const ushort* __restrict__ Wie,    // (3072,2048) bf16
    const float*  __restrict__ bhq,    // (4096)
    const float*  __restrict__ vvec,   // (1024)
    const float*  __restrict__ giemb,  // (B*T,3H) fp32 (incl b_ih)
    float* __restrict__ qgh,           // (B,4096)
    float* __restrict__ scores,        // (B,S)
    ushort* __restrict__ ctx,          // (B,ENC) bf16
    float* __restrict__ hall_f,        // (B,T,H)
    ushort* __restrict__ hall_b,       // (B,T,H)
    unsigned* __restrict__ flags,      // barrier flags
    unsigned* __restrict__ go)         // barrier go word
{
    const int blk = blockIdx.x;
    const int tid = threadIdx.x;
    const int wv = tid >> 6;
    const int lane = tid & 63;
    const int frow = lane & 15;
    const int fk = (lane >> 4) * 8;

    __shared__ __align__(16) char smem_raw[28672];

    unsigned gen = 0;

    for (int t = 0; t < T_; ++t) {
        const ushort* hb = t ? (hall_b + (size_t)(t - 1) * H_) : ench;
        const float*  hf = t ? (hall_f + (size_t)(t - 1) * H_) : ench_f;
        const int ldh = t ? (T_ * H_) : H_;

        // ---------------- P1: qgh ----------------
        {
            f32x4 (*red)[64] = reinterpret_cast<f32x4(*)[64]>(smem_raw);
            const int n0 = blk * 16;
            const int mt = wv & 3;      // m-tile (16 rows)
            const int kh = wv >> 2;     // K-half
            const ushort* Arow = hb + (size_t)(mt * 16 + frow) * ldh + kh * 512 + fk;
            const ushort* Brow = Whq + (size_t)(n0 + frow) * H_ + kh * 512 + fk;
            f32x4 acc = (f32x4){0.f, 0.f, 0.f, 0.f};
#pragma unroll
            for (int c = 0; c < 16; ++c) {
                bf16x8 a = *reinterpret_cast<const bf16x8*>(Arow + c * 32);
                bf16x8 b = *reinterpret_cast<const bf16x8*>(Brow + c * 32);
                acc = __builtin_amdgcn_mfma_f32_16x16x32_bf16(a, b, acc, 0, 0, 0);
            }
            red[wv][lane] = acc;
            __syncthreads();
            if (wv < 4) {
                f32x4 s = red[wv][lane] + red[wv + 4][lane];
                const int col = n0 + frow;
                const float bv = bhq[col];
                const int row0 = wv * 16 + (lane >> 4) * 4;
#pragma unroll
                for (int r = 0; r < 4; ++r)
                    qgh[(size_t)(row0 + r) * QGH_ + col] = s[r] + bv;
            }
        }
        gbar(flags, go, ++gen);

        // ---------------- P2: scores (register q/v, no LDS) ----------------
        {
            const int b = blk >> 2;
            const int s0 = (blk & 3) * 32;
            const int h0 = lane * 16;
            float qr[16], vr[16];
#pragma unroll
            for (int j = 0; j < 16; j += 4) {
                *reinterpret_cast<f32x4*>(&qr[j]) =
                    *reinterpret_cast<const f32x4*>(qgh + (size_t)b * QGH_ + h0 + j);
                *reinterpret_cast<f32x4*>(&vr[j]) =
                    *reinterpret_cast<const f32x4*>(vvec + h0 + j);
            }
#pragma unroll
            for (int i = 0; i < 4; ++i) {
                const int s = s0 + wv * 4 + i;
                const ushort* ep = encp + ((size_t)b * S_ + s) * H_ + h0;
                u16x8 e0 = *reinterpret_cast<const u16x8*>(ep);
                u16x8 e1 = *reinterpret_cast<const u16x8*>(ep + 8);
                float p = 0.f;
#pragma unroll
                for (int j = 0; j < 8; ++j)
                    p += vr[j] * tanhf(qr[j] + bf2f(e0[j]));
#pragma unroll
                for (int j = 0; j < 8; ++j)
                    p += vr[8 + j] * tanhf(qr[8 + j] + bf2f(e1[j]));
#pragma unroll
                for (int off = 32; off; off >>= 1) p += __shfl_xor(p, off);
                if (lane == 0) scores[b * S_ + s] = p;
            }
        }
        gbar(flags, go, ++gen);

        // ---------------- P3: softmax + ctx ----------------
        {
            float* al = reinterpret_cast<float*>(smem_raw);
            const int b = blk >> 2;
            const int e0 = (blk & 3) * 512;
            if (tid < 64) {
                float a0 = scores[b * S_ + tid];
                float a1 = scores[b * S_ + tid + 64];
                float m = fmaxf(a0, a1);
#pragma unroll
                for (int off = 32; off; off >>= 1) m = fmaxf(m, __shfl_xor(m, off));
                float e0v = expf(a0 - m), e1v = expf(a1 - m);
                float ssum = e0v + e1v;
#pragma unroll
                for (int off = 32; off; off >>= 1) ssum += __shfl_xor(ssum, off);
                const float inv = 1.f / ssum;
                al[tid] = e0v * inv;
                al[tid + 64] = e1v * inv;
            }
            __syncthreads();
            const int e = e0 + tid;
            const ushort* eb = enc + (size_t)b * S_ * ENC_ + e;
            float acc = 0.f;
#pragma unroll 8
            for (int s = 0; s < S_; ++s)
                acc = fmaf(al[s], bf2f(eb[(size_t)s * ENC_]), acc);
            ctx[(size_t)b * ENC_ + e] = f2bf(acc);
        }
        gbar(flags, go, ++gen);

        // ---------------- P4: gi (3 gates) + GRU ----------------
        {
            f32x4 (*redp)[3][64] = reinterpret_cast<f32x4(*)[3][64]>(smem_raw);
            float (*gt)[16][16] = reinterpret_cast<float(*)[16][16]>(smem_raw + 24576);
            const int jt = blk >> 2;     // j-slice 0..63
            const int mq = blk & 3;      // b-quarter
            const int b0 = mq * 16;
            const int kc = wv * 256;     // K-chunk per wave

            const ushort* Arow = ctx + (size_t)(b0 + frow) * ENC_ + kc + fk;
            const ushort* Brow = Wie + (size_t)(jt * 16 + frow) * ENC_ + kc + fk;
            f32x4 a0 = (f32x4){0.f, 0.f, 0.f, 0.f};
            f32x4 a1 = a0, a2 = a0;
#pragma unroll
            for (int c = 0; c < 8; ++c) {
                bf16x8 av = *reinterpret_cast<const bf16x8*>(Arow + c * 32);
                bf16x8 br = *reinterpret_cast<const bf16x8*>(Brow + c * 32);
                bf16x8 bz = *reinterpret_cast<const bf16x8*>(Brow + (size_t)1024 * ENC_ + c * 32);
                bf16x8 bn = *reinterpret_cast<const bf16x8*>(Brow + (size_t)2048 * ENC_ + c * 32);
                a0 = __builtin_amdgcn_mfma_f32_16x16x32_bf16(av, br, a0, 0, 0, 0);
                a1 = __builtin_amdgcn_mfma_f32_16x16x32_bf16(av, bz, a1, 0, 0, 0);
                a2 = __builtin_amdgcn_mfma_f32_16x16x32_bf16(av, bn, a2, 0, 0, 0);
            }
            redp[wv][0][lane] = a0;
            redp[wv][1][lane] = a1;
            redp[wv][2][lane] = a2;
            __syncthreads();
            if (wv < 3) {
                f32x4 s = redp[0][wv][lane];
#pragma unroll
                for (int w = 1; w < 8; ++w) s += redp[w][wv][lane];
                const int row0 = (lane >> 4) * 4;
#pragma unroll
                for (int r = 0; r < 4; ++r) gt[wv][row0 + r][frow] = s[r];
            }
            __syncthreads();
            if (tid < 256) {
                const int bl = tid >> 4, jl = tid & 15;
                const int b = b0 + bl;
                const int j = jt * 16 + jl;
                const size_t gr = (size_t)(b * T_ + t) * G3_;
                const float ir  = gt[0][bl][jl] + giemb[gr + j];
                const float iz  = gt[1][bl][jl] + giemb[gr + H_ + j];
                const float in_ = gt[2][bl][jl] + giemb[gr + 2 * H_ + j];
                const float* ghp = qgh + (size_t)b * QGH_ + H_;
                const float r = sigmoidf_(ir + ghp[j]);
                const float z = sigmoidf_(iz + ghp[H_ + j]);
                const float n = tanhf(in_ + r * ghp[2 * H_ + j]);
                const float hnew = (1.f - z) * n + z * hf[(size_t)b * ldh + j];
                const size_t ho = (size_t)b * (T_ * H_) + (size_t)t * H_ + j;
                hall_f[ho] = hnew;
                hall_b[ho] = f2bf(hnew);
            }
        }
        gbar(flags, go, ++gen);
    }
}

// ---------------------------------------------------------------------------
static inline int pgrid(size_t total) {
    size_t nb = (total + 255) / 256;
    if (nb > 4096) nb = 4096;
    return (int)nb;
}

extern "C" void kernel_launch(void* const* d_in, const int* in_sizes, int n_in,
                              void* d_out, int out_size, void* d_ws, size_t ws_size,
                              hipStream_t stream) {
    const float* enc    = (const float*)d_in[0];
    const float* enc_h  = (const float*)d_in[1];
    const int*   target = (const int*)  d_in[2];
    const float* emb    = (const float*)d_in[3];
    const float* Wa     = (const float*)d_in[4];
    const float* ba     = (const float*)d_in[5];
    const float* vvec   = (const float*)d_in[6];
    const float* W_ih   = (const float*)d_in[7];
    const float* b_ih   = (const float*)d_in[8];
    const float* W_hh   = (const float*)d_in[9];
    const float* b_hh   = (const float*)d_in[10];
    const float* Wo     = (const float*)d_in[11];
    const float* bo     = (const float*)d_in[12];
    float* out = (float*)d_out;

    char* p = (char*)d_ws;
    auto alloc_u16 = [&](size_t n) { ushort* r = (ushort*)p; p += n * 2; return r; };
    auto alloc_f32 = [&](size_t n) { float* r = (float*)p; p += n * 4; return r; };

    ushort* enc_bf  = alloc_u16((size_t)B_ * S_ * ENC_);
    ushort* encp_bf = alloc_u16((size_t)B_ * S_ * H_);
    ushort* Wo_bf   = alloc_u16((size_t)V_ * H_);
    ushort* Wae_bf  = alloc_u16((size_t)H_ * ENC_);
    ushort* Whq_bf  = alloc_u16((size_t)QGH_ * H_);
    ushort* Wie_bf  = alloc_u16((size_t)G3_ * ENC_);
    ushort* Wiee_bf = alloc_u16((size_t)G3_ * E_);
    ushort* ench_bf = alloc_u16((size_t)B_ * H_);
    ushort* Xemb_bf = alloc_u16((size_t)B_ * T_ * E_);
    ushort* hall_bf = alloc_u16((size_t)B_ * T_ * H_);
    ushort* ctx_bf  = alloc_u16((size_t)B_ * ENC_);
    float* hall_f   = alloc_f32((size_t)B_ * T_ * H_);
    float* giemb    = alloc_f32((size_t)B_ * T_ * G3_);
    float* qgh      = alloc_f32((size_t)B_ * QGH_);
    float* bhq      = alloc_f32((size_t)QGH_);
    float* scores   = alloc_f32((size_t)B_ * S_);
    unsigned* flags = (unsigned*)alloc_f32(8448);  // 256*32 flags + go + slack
    unsigned* go    = flags + 8192;

    const int LDW = H_ + ENC_;   // 3072

    // ---- packs ----
    pack_bf16<<<pgrid((size_t)B_*S_*ENC_), 256, 0, stream>>>(enc, ENC_, 0, ENC_, enc_bf, (size_t)B_*S_*ENC_);
    pack_bf16<<<pgrid((size_t)V_*H_), 256, 0, stream>>>(Wo, H_, 0, H_, Wo_bf, (size_t)V_*H_);
    pack_bf16<<<pgrid((size_t)H_*ENC_), 256, 0, stream>>>(Wa, LDW, H_, ENC_, Wae_bf, (size_t)H_*ENC_);
    pack_bf16<<<pgrid((size_t)H_*H_), 256, 0, stream>>>(Wa, LDW, 0, H_, Whq_bf, (size_t)H_*H_);
    pack_bf16<<<pgrid((size_t)G3_*H_), 256, 0, stream>>>(W_hh, H_, 0, H_, Whq_bf + (size_t)H_*H_, (size_t)G3_*H_);
    pack_bf16<<<pgrid((size_t)G3_*ENC_), 256, 0, stream>>>(W_ih, XDIM_, E_, ENC_, Wie_bf, (size_t)G3_*ENC_);
    pack_bf16<<<pgrid((size_t)G3_*E_), 256, 0, stream>>>(W_ih, XDIM_, 0, E_, Wiee_bf, (size_t)G3_*E_);
    pack_bf16<<<pgrid((size_t)B_*H_), 256, 0, stream>>>(enc_h, H_, 0, H_, ench_bf, (size_t)B_*H_);
    gather_emb<<<B_*T_, 256, 0, stream>>>(target, emb, Xemb_bf);
    pack_bhq<<<QGH_/256, 256, 0, stream>>>(ba, b_hh, bhq);
    barinit<<<33, 256, 0, stream>>>(flags);

    // ---- big parallel GEMMs ----
    gemm128_bf16<<<dim3(H_/128, (B_*S_)/128), 256, 0, stream>>>(
        enc_bf, ENC_, Wae_bf, ENC_, nullptr, nullptr, encp_bf, H_, ENC_);
    gemm128_bf16<<<dim3(G3_/128, (B_*T_)/128), 256, 0, stream>>>(
        Xemb_bf, E_, Wiee_bf, E_, b_ih, giemb, nullptr, G3_, E_);

    // ---- persistent recurrence ----
    decoder_persist<<<NB_, 512, 0, stream>>>(
        encp_bf, enc_bf, ench_bf, enc_h, Whq_bf, Wie_bf, bhq, vvec, giemb,
        qgh, scores, ctx_bf, hall_f, hall_bf, flags, go);

    // ---- output projection ----
    gemm128_bf16<<<dim3(V_/128, (B_*T_)/128), 256, 0, stream>>>(
        hall_bf, H_, Wo_bf, H_, bo, out, nullptr, V_, H_);
}

// Round 6
// 5027.486 us; speedup vs baseline: 2.2815x; 1.4905x over previous
//
#include <hip/hip_runtime.h>
#include <hip/hip_bf16.h>

#define B_   64
#define S_   128
#define T_   64
#define H_   1024
#define E_   512
#define V_   16000
#define ENC_ 2048
#define XDIM_ (E_ + ENC_)   // 2560
#define G3_  (3 * H_)       // 3072
#define QGH_ (4 * H_)       // 4096 (q | gh)
#define NB_  256            // persistent grid size

typedef __attribute__((ext_vector_type(8))) short bf16x8;
typedef __attribute__((ext_vector_type(8))) unsigned short u16x8;
typedef __attribute__((ext_vector_type(4))) unsigned short u16x4;
typedef __attribute__((ext_vector_type(4))) float f32x4;

__device__ __forceinline__ ushort f2bf(float x) {
    __hip_bfloat16 h = __float2bfloat16(x);
    return *reinterpret_cast<ushort*>(&h);
}
__device__ __forceinline__ float bf2f(ushort u) {
    return __uint_as_float((unsigned)u << 16);
}
__device__ __forceinline__ float sigmoidf_(float x) {
    return 1.f / (1.f + expf(-x));
}

// async global->LDS, 16B per lane
__device__ __forceinline__ void gload_lds16(const ushort* g, ushort* l) {
    __builtin_amdgcn_global_load_lds(
        (const __attribute__((address_space(1))) unsigned int*)g,
        (__attribute__((address_space(3))) unsigned int*)l, 16, 0, 0);
}

// ---------------------------------------------------------------------------
// Contention-free grid barrier, NO acquire-invalidate.
// Safe because all cross-block mutable data is written to step-unique
// addresses (consumer caches can't hold stale lines) and producers publish
// via RELEASE flag stores (wbl2 -> LLC; writeback only, no eviction of the
// clean L2-resident weights).
// ---------------------------------------------------------------------------
__device__ __forceinline__ void gbar(unsigned* flags, unsigned* go, unsigned gen) {
    __syncthreads();
    const int tid = threadIdx.x;
    if (blockIdx.x == 0) {
        if (tid >= 1 && tid < NB_) {
            while (__hip_atomic_load(&flags[tid * 32], __ATOMIC_RELAXED,
                                     __HIP_MEMORY_SCOPE_AGENT) < gen)
                __builtin_amdgcn_s_sleep(1);
        }
        __syncthreads();   // all 255 flags observed
        if (tid == 0) {
            // RELEASE publishes block0's own phase writes (wbl2 to LLC)
            __hip_atomic_store(go, gen, __ATOMIC_RELEASE, __HIP_MEMORY_SCOPE_AGENT);
        }
    } else {
        if (tid == 0) {
            // RELEASE publishes this block's phase writes (wbl2 to LLC)
            __hip_atomic_store(&flags[blockIdx.x * 32], gen, __ATOMIC_RELEASE,
                               __HIP_MEMORY_SCOPE_AGENT);
            while (__hip_atomic_load(go, __ATOMIC_RELAXED,
                                     __HIP_MEMORY_SCOPE_AGENT) < gen)
                __builtin_amdgcn_s_sleep(1);
        }
    }
    __syncthreads();
}

// ---------------------------------------------------------------------------
// m97-structure GEMM: C[M,N] = A[M,K] @ W[N,K]^T + bias[N]
// ---------------------------------------------------------------------------
__global__ __launch_bounds__(256) void gemm128_bf16(
    const ushort* __restrict__ A, int lda,
    const ushort* __restrict__ W, int ldw,
    const float* __restrict__ bias,
    float* __restrict__ Cf, ushort* __restrict__ Cb, int ldc,
    int K)
{
    const int bn0 = blockIdx.x * 128;
    const int bm0 = blockIdx.y * 128;
    const int tid = threadIdx.x;
    const int wv  = tid >> 6;
    const int lane = tid & 63;

    __shared__ ushort As[128 * 32];
    __shared__ ushort Bs[128 * 32];

    const int srow = tid >> 2;
    const int scol = (tid & 3) * 8;

    const ushort* gA0 = A + (size_t)(bm0 + srow) * lda + scol;
    const ushort* gA1 = gA0 + (size_t)64 * lda;
    const ushort* gB0 = W + (size_t)(bn0 + srow) * ldw + scol;
    const ushort* gB1 = gB0 + (size_t)64 * ldw;

    ushort* lA0 = &As[tid * 8];
    ushort* lA1 = &As[2048 + tid * 8];
    ushort* lB0 = &Bs[tid * 8];
    ushort* lB1 = &Bs[2048 + tid * 8];

    const int wr0 = (wv >> 1) * 64;
    const int wc0 = (wv & 1) * 64;
    const int frow = lane & 15;
    const int fk   = (lane >> 4) * 8;

    f32x4 acc[4][4];
#pragma unroll
    for (int i = 0; i < 4; ++i)
#pragma unroll
        for (int j = 0; j < 4; ++j) acc[i][j] = (f32x4){0.f, 0.f, 0.f, 0.f};

    for (int k0 = 0; k0 < K; k0 += 32) {
        gload_lds16(gA0 + k0, lA0);
        gload_lds16(gA1 + k0, lA1);
        gload_lds16(gB0 + k0, lB0);
        gload_lds16(gB1 + k0, lB1);
        __syncthreads();

        bf16x8 af[4], bf[4];
#pragma unroll
        for (int rb = 0; rb < 4; ++rb)
            af[rb] = *reinterpret_cast<const bf16x8*>(&As[(wr0 + rb * 16 + frow) * 32 + fk]);
#pragma unroll
        for (int cb = 0; cb < 4; ++cb)
            bf[cb] = *reinterpret_cast<const bf16x8*>(&Bs[(wc0 + cb * 16 + frow) * 32 + fk]);
#pragma unroll
        for (int rb = 0; rb < 4; ++rb)
#pragma unroll
            for (int cb = 0; cb < 4; ++cb)
                acc[rb][cb] = __builtin_amdgcn_mfma_f32_16x16x32_bf16(af[rb], bf[cb], acc[rb][cb], 0, 0, 0);
        __syncthreads();
    }

    const int quad = lane >> 4;
#pragma unroll
    for (int cb = 0; cb < 4; ++cb) {
        const int col = bn0 + wc0 + cb * 16 + frow;
        const float bv = bias ? bias[col] : 0.f;
#pragma unroll
        for (int rb = 0; rb < 4; ++rb) {
            const int row0 = bm0 + wr0 + rb * 16 + quad * 4;
            f32x4 a = acc[rb][cb];
#pragma unroll
            for (int r = 0; r < 4; ++r) {
                const float val = a[r] + bv;
                if (Cb) Cb[(size_t)(row0 + r) * ldc + col] = f2bf(val);
                else    Cf[(size_t)(row0 + r) * ldc + col] = val;
            }
        }
    }
}

// ---------------------------------------------------------------------------
// Packs
// ---------------------------------------------------------------------------
__global__ __launch_bounds__(256) void pack_bf16(
    const float* __restrict__ src, int src_ld, int c0, int ncols,
    ushort* __restrict__ dst, size_t total)
{
    size_t i = (size_t)blockIdx.x * 256 + threadIdx.x;
    const size_t stride = (size_t)gridDim.x * 256;
    for (; i < total; i += stride) {
        size_t r = i / (size_t)ncols;
        int c = (int)(i - r * (size_t)ncols);
        dst[i] = f2bf(src[r * (size_t)src_ld + c0 + c]);
    }
}

__global__ __launch_bounds__(256) void gather_emb(
    const int* __restrict__ target, const float* __restrict__ emb,
    ushort* __restrict__ dst)
{
    const int row = blockIdx.x;          // b*T + t
    const int b = row >> 6;
    const int t = row & 63;
    const int tok = (t == 0) ? 1 : target[b * T_ + t - 1];
    const float* e = emb + (size_t)tok * E_;
    ushort* d = dst + (size_t)row * E_;
    for (int c = threadIdx.x; c < E_; c += 256) d[c] = f2bf(e[c]);
}

__global__ __launch_bounds__(256) void pack_bhq(
    const float* __restrict__ ba, const float* __restrict__ bhh,
    float* __restrict__ dst)
{
    const int j = blockIdx.x * 256 + threadIdx.x;
    if (j < H_) dst[j] = ba[j];
    else if (j < QGH_) dst[j] = bhh[j - H_];
}

// zero flags (256*32) + go (1) -> zero 8448 for slack
__global__ __launch_bounds__(256) void barinit(unsigned* f) {
    const int i = blockIdx.x * 256 + threadIdx.x;
    if (i < 8448) f[i] = 0u;
}

// ---------------------------------------------------------------------------
// Persistent decoder: whole T=64 recurrence. 256 blocks x 512 threads,
// 3 flag-barriers per step. qgh/ctx are STEP-UNIQUE (indexed by t).
// ---------------------------------------------------------------------------
__global__ __launch_bounds__(512) void decoder_persist(
    const ushort* __restrict__ encp,   // (B,S,H) bf16
    const ushort* __restrict__ enc,    // (B,S,ENC) bf16
    const ushort* __restrict__ ench,   // (B,H) bf16 h0
    const float*  __restrict__ ench_f, // (B,H) fp32 h0
    const ushort* __restrict__ Whq,    // (4096,1024) bf16
    const ushort* __restrict__ Wie,    // (3072,2048) bf16
    const float*  __restrict__ bhq,    // (4096)
    const float*  __restrict__ vvec,   // (1024)
    const float*  __restrict__ giemb,  // (B*T,3H) fp32 (incl b_ih)
    float* __restrict__ qgh_all,       // (T,B,4096) step-unique
    ushort* __restrict__ ctx_all,      // (T,B,ENC) bf16 step-unique
    float* __restrict__ hall_f,        // (B,T,H)
    ushort* __restrict__ hall_b,       // (B,T,H)
    unsigned* __restrict__ flags,      // barrier flags
    unsigned* __restrict__ go)         // barrier go word
{
    const int blk = blockIdx.x;
    const int tid = threadIdx.x;
    const int wv = tid >> 6;
    const int lane = tid & 63;
    const int frow = lane & 15;
    const int fk = (lane >> 4) * 8;

    __shared__ __align__(16) char smem_raw[28672];

    unsigned gen = 0;

    for (int t = 0; t < T_; ++t) {
        const ushort* hb = t ? (hall_b + (size_t)(t - 1) * H_) : ench;
        const float*  hf = t ? (hall_f + (size_t)(t - 1) * H_) : ench_f;
        const int ldh = t ? (T_ * H_) : H_;
        float* qgh = qgh_all + (size_t)t * B_ * QGH_;
        ushort* ctx = ctx_all + (size_t)t * B_ * ENC_;

        // ---------------- P1: qgh ----------------
        {
            f32x4 (*red)[64] = reinterpret_cast<f32x4(*)[64]>(smem_raw);
            const int n0 = blk * 16;
            const int mt = wv & 3;      // m-tile (16 rows)
            const int kh = wv >> 2;     // K-half
            const ushort* Arow = hb + (size_t)(mt * 16 + frow) * ldh + kh * 512 + fk;
            const ushort* Brow = Whq + (size_t)(n0 + frow) * H_ + kh * 512 + fk;
            f32x4 acc = (f32x4){0.f, 0.f, 0.f, 0.f};
#pragma unroll
            for (int c = 0; c < 16; ++c) {
                bf16x8 a = *reinterpret_cast<const bf16x8*>(Arow + c * 32);
                bf16x8 b = *reinterpret_cast<const bf16x8*>(Brow + c * 32);
                acc = __builtin_amdgcn_mfma_f32_16x16x32_bf16(a, b, acc, 0, 0, 0);
            }
            red[wv][lane] = acc;
            __syncthreads();
            if (wv < 4) {
                f32x4 s = red[wv][lane] + red[wv + 4][lane];
                const int col = n0 + frow;
                const float bv = bhq[col];
                const int row0 = wv * 16 + (lane >> 4) * 4;
#pragma unroll
                for (int r = 0; r < 4; ++r)
                    qgh[(size_t)(row0 + r) * QGH_ + col] = s[r] + bv;
            }
        }
        gbar(flags, go, ++gen);

        // ---------------- P23: scores + softmax + ctx (blocks 0..63) ----------------
        if (blk < B_) {
            float* sc = reinterpret_cast<float*>(smem_raw);        // [128]
            float* al = sc + S_;                                   // [128]
            const int b = blk;
            const int h0 = lane * 16;
            float qr[16], vr[16];
#pragma unroll
            for (int j = 0; j < 16; j += 4) {
                *reinterpret_cast<f32x4*>(&qr[j]) =
                    *reinterpret_cast<const f32x4*>(qgh + (size_t)b * QGH_ + h0 + j);
                *reinterpret_cast<f32x4*>(&vr[j]) =
                    *reinterpret_cast<const f32x4*>(vvec + h0 + j);
            }
            // scores: 8 waves x 16 s each
            for (int s = wv; s < S_; s += 8) {
                const ushort* ep = encp + ((size_t)b * S_ + s) * H_ + h0;
                u16x8 e0 = *reinterpret_cast<const u16x8*>(ep);
                u16x8 e1 = *reinterpret_cast<const u16x8*>(ep + 8);
                float p = 0.f;
#pragma unroll
                for (int j = 0; j < 8; ++j)
                    p += vr[j] * tanhf(qr[j] + bf2f(e0[j]));
#pragma unroll
                for (int j = 0; j < 8; ++j)
                    p += vr[8 + j] * tanhf(qr[8 + j] + bf2f(e1[j]));
#pragma unroll
                for (int off = 32; off; off >>= 1) p += __shfl_xor(p, off);
                if (lane == 0) sc[s] = p;
            }
            __syncthreads();
            if (tid < 64) {
                float a0 = sc[tid], a1 = sc[tid + 64];
                float m = fmaxf(a0, a1);
#pragma unroll
                for (int off = 32; off; off >>= 1) m = fmaxf(m, __shfl_xor(m, off));
                float e0v = expf(a0 - m), e1v = expf(a1 - m);
                float ssum = e0v + e1v;
#pragma unroll
                for (int off = 32; off; off >>= 1) ssum += __shfl_xor(ssum, off);
                const float inv = 1.f / ssum;
                al[tid] = e0v * inv;
                al[tid + 64] = e1v * inv;
            }
            __syncthreads();
            // ctx: thread owns 4 cols
            const int c0 = tid * 4;
            const ushort* eb = enc + (size_t)b * S_ * ENC_ + c0;
            f32x4 acc = (f32x4){0.f, 0.f, 0.f, 0.f};
#pragma unroll 8
            for (int s = 0; s < S_; ++s) {
                u16x4 u = *reinterpret_cast<const u16x4*>(eb + (size_t)s * ENC_);
                const float a = al[s];
                acc[0] = fmaf(a, bf2f(u[0]), acc[0]);
                acc[1] = fmaf(a, bf2f(u[1]), acc[1]);
                acc[2] = fmaf(a, bf2f(u[2]), acc[2]);
                acc[3] = fmaf(a, bf2f(u[3]), acc[3]);
            }
            u16x4 o;
            o[0] = f2bf(acc[0]); o[1] = f2bf(acc[1]);
            o[2] = f2bf(acc[2]); o[3] = f2bf(acc[3]);
            *reinterpret_cast<u16x4*>(ctx + (size_t)b * ENC_ + c0) = o;
        }
        gbar(flags, go, ++gen);

        // ---------------- P4: gi (3 gates) + GRU ----------------
        {
            f32x4 (*redp)[3][64] = reinterpret_cast<f32x4(*)[3][64]>(smem_raw);
            float (*gt)[16][16] = reinterpret_cast<float(*)[16][16]>(smem_raw + 24576);
            const int jt = blk >> 2;     // j-slice 0..63
            const int mq = blk & 3;      // b-quarter
            const int b0 = mq * 16;
            const int kc = wv * 256;     // K-chunk per wave

            const ushort* Arow = ctx + (size_t)(b0 + frow) * ENC_ + kc + fk;
            const ushort* Brow = Wie + (size_t)(jt * 16 + frow) * ENC_ + kc + fk;
            f32x4 a0 = (f32x4){0.f, 0.f, 0.f, 0.f};
            f32x4 a1 = a0, a2 = a0;
#pragma unroll
            for (int c = 0; c < 8; ++c) {
                bf16x8 av = *reinterpret_cast<const bf16x8*>(Arow + c * 32);
                bf16x8 br = *reinterpret_cast<const bf16x8*>(Brow + c * 32);
                bf16x8 bz = *reinterpret_cast<const bf16x8*>(Brow + (size_t)1024 * ENC_ + c * 32);
                bf16x8 bn = *reinterpret_cast<const bf16x8*>(Brow + (size_t)2048 * ENC_ + c * 32);
                a0 = __builtin_amdgcn_mfma_f32_16x16x32_bf16(av, br, a0, 0, 0, 0);
                a1 = __builtin_amdgcn_mfma_f32_16x16x32_bf16(av, bz, a1, 0, 0, 0);
                a2 = __builtin_amdgcn_mfma_f32_16x16x32_bf16(av, bn, a2, 0, 0, 0);
            }
            redp[wv][0][lane] = a0;
            redp[wv][1][lane] = a1;
            redp[wv][2][lane] = a2;
            __syncthreads();
            if (wv < 3) {
                f32x4 s = redp[0][wv][lane];
#pragma unroll
                for (int w = 1; w < 8; ++w) s += redp[w][wv][lane];
                const int row0 = (lane >> 4) * 4;
#pragma unroll
                for (int r = 0; r < 4; ++r) gt[wv][row0 + r][frow] = s[r];
            }
            __syncthreads();
            if (tid < 256) {
                const int bl = tid >> 4, jl = tid & 15;
                const int b = b0 + bl;
                const int j = jt * 16 + jl;
                const size_t gr = (size_t)(b * T_ + t) * G3_;
                const float ir  = gt[0][bl][jl] + giemb[gr + j];
                const float iz  = gt[1][bl][jl] + giemb[gr + H_ + j];
                const float in_ = gt[2][bl][jl] + giemb[gr + 2 * H_ + j];
                const float* ghp = qgh + (size_t)b * QGH_ + H_;
                const float r = sigmoidf_(ir + ghp[j]);
                const float z = sigmoidf_(iz + ghp[H_ + j]);
                const float n = tanhf(in_ + r * ghp[2 * H_ + j]);
                const float hnew = (1.f - z) * n + z * hf[(size_t)b * ldh + j];
                const size_t ho = (size_t)b * (T_ * H_) + (size_t)t * H_ + j;
                hall_f[ho] = hnew;
                hall_b[ho] = f2bf(hnew);
            }
        }
        gbar(flags, go, ++gen);
    }
}

// ---------------------------------------------------------------------------
static inline int pgrid(size_t total) {
    size_t nb = (total + 255) / 256;
    if (nb > 4096) nb = 4096;
    return (int)nb;
}

extern "C" void kernel_launch(void* const* d_in, const int* in_sizes, int n_in,
                              void* d_out, int out_size, void* d_ws, size_t ws_size,
                              hipStream_t stream) {
    const float* enc    = (const float*)d_in[0];
    const float* enc_h  = (const float*)d_in[1];
    const int*   target = (const int*)  d_in[2];
    const float* emb    = (const float*)d_in[3];
    const float* Wa     = (const float*)d_in[4];
    const float* ba     = (const float*)d_in[5];
    const float* vvec   = (const float*)d_in[6];
    const float* W_ih   = (const float*)d_in[7];
    const float* b_ih   = (const float*)d_in[8];
    const float* W_hh   = (const float*)d_in[9];
    const float* b_hh   = (const float*)d_in[10];
    const float* Wo     = (const float*)d_in[11];
    const float* bo     = (const float*)d_in[12];
    float* out = (float*)d_out;

    char* p = (char*)d_ws;
    auto alloc_u16 = [&](size_t n) { ushort* r = (ushort*)p; p += n * 2; return r; };
    auto alloc_f32 = [&](size_t n) { float* r = (float*)p; p += n * 4; return r; };

    ushort* enc_bf  = alloc_u16((size_t)B_ * S_ * ENC_);
    ushort* encp_bf = alloc_u16((size_t)B_ * S_ * H_);
    ushort* Wo_bf   = alloc_u16((size_t)V_ * H_);
    ushort* Wae_bf  = alloc_u16((size_t)H_ * ENC_);
    ushort* Whq_bf  = alloc_u16((size_t)QGH_ * H_);
    ushort* Wie_bf  = alloc_u16((size_t)G3_ * ENC_);
    ushort* Wiee_bf = alloc_u16((size_t)G3_ * E_);
    ushort* ench_bf = alloc_u16((size_t)B_ * H_);
    ushort* Xemb_bf = alloc_u16((size_t)B_ * T_ * E_);
    ushort* hall_bf = alloc_u16((size_t)B_ * T_ * H_);
    ushort* ctx_all = alloc_u16((size_t)T_ * B_ * ENC_);   // step-unique, 16MB
    float* hall_f   = alloc_f32((size_t)B_ * T_ * H_);
    float* giemb    = alloc_f32((size_t)B_ * T_ * G3_);
    float* qgh_all  = alloc_f32((size_t)T_ * B_ * QGH_);   // step-unique, 64MB
    float* bhq      = alloc_f32((size_t)QGH_);
    unsigned* flags = (unsigned*)alloc_f32(8448);  // 256*32 flags + go + slack
    unsigned* go    = flags + 8192;

    const int LDW = H_ + ENC_;   // 3072

    // ---- packs ----
    pack_bf16<<<pgrid((size_t)B_*S_*ENC_), 256, 0, stream>>>(enc, ENC_, 0, ENC_, enc_bf, (size_t)B_*S_*ENC_);
    pack_bf16<<<pgrid((size_t)V_*H_), 256, 0, stream>>>(Wo, H_, 0, H_, Wo_bf, (size_t)V_*H_);
    pack_bf16<<<pgrid((size_t)H_*ENC_), 256, 0, stream>>>(Wa, LDW, H_, ENC_, Wae_bf, (size_t)H_*ENC_);
    pack_bf16<<<pgrid((size_t)H_*H_), 256, 0, stream>>>(Wa, LDW, 0, H_, Whq_bf, (size_t)H_*H_);
    pack_bf16<<<pgrid((size_t)G3_*H_), 256, 0, stream>>>(W_hh, H_, 0, H_, Whq_bf + (size_t)H_*H_, (size_t)G3_*H_);
    pack_bf16<<<pgrid((size_t)G3_*ENC_), 256, 0, stream>>>(W_ih, XDIM_, E_, ENC_, Wie_bf, (size_t)G3_*ENC_);
    pack_bf16<<<pgrid((size_t)G3_*E_), 256, 0, stream>>>(W_ih, XDIM_, 0, E_, Wiee_bf, (size_t)G3_*E_);
    pack_bf16<<<pgrid((size_t)B_*H_), 256, 0, stream>>>(enc_h, H_, 0, H_, ench_bf, (size_t)B_*H_);
    gather_emb<<<B_*T_, 256, 0, stream>>>(target, emb, Xemb_bf);
    pack_bhq<<<QGH_/256, 256, 0, stream>>>(ba, b_hh, bhq);
    barinit<<<33, 256, 0, stream>>>(flags);

    // ---- big parallel GEMMs ----
    gemm128_bf16<<<dim3(H_/128, (B_*S_)/128), 256, 0, stream>>>(
        enc_bf, ENC_, Wae_bf, ENC_, nullptr, nullptr, encp_bf, H_, ENC_);
    gemm128_bf16<<<dim3(G3_/128, (B_*T_)/128), 256, 0, stream>>>(
        Xemb_bf, E_, Wiee_bf, E_, b_ih, giemb, nullptr, G3_, E_);

    // ---- persistent recurrence ----
    decoder_persist<<<NB_, 512, 0, stream>>>(
        encp_bf, enc_bf, ench_bf, enc_h, Whq_bf, Wie_bf, bhq, vvec, giemb,
        qgh_all, ctx_all, hall_f, hall_bf, flags, go);

    // ---- output projection ----
    gemm128_bf16<<<dim3(V_/128, (B_*T_)/128), 256, 0, stream>>>(
        hall_bf, H_, Wo_bf, H_, bo, out, nullptr, V_, H_);
}

// Round 7
// 3624.572 us; speedup vs baseline: 3.1646x; 1.3871x over previous
//
#include <hip/hip_runtime.h>
#include <hip/hip_bf16.h>

#define B_   64
#define S_   128
#define T_   64
#define H_   1024
#define E_   512
#define V_   16000
#define ENC_ 2048
#define XDIM_ (E_ + ENC_)   // 2560
#define G3_  (3 * H_)       // 3072
#define QGH_ (4 * H_)       // 4096 (q | gh)
#define NB_  256            // persistent grid size

// dynamic LDS layout (bytes)
#define SMEM_ENCP   0        // 32 rows x 2048 B = 65536
#define SMEM_SCR    65536    // phase scratch (max 27648)
#define SMEM_TOTAL  93184

typedef __attribute__((ext_vector_type(8))) short bf16x8;
typedef __attribute__((ext_vector_type(8))) unsigned short u16x8;
typedef __attribute__((ext_vector_type(4))) unsigned short u16x4;
typedef __attribute__((ext_vector_type(4))) float f32x4;

__device__ __forceinline__ ushort f2bf(float x) {
    __hip_bfloat16 h = __float2bfloat16(x);
    return *reinterpret_cast<ushort*>(&h);
}
__device__ __forceinline__ float bf2f(ushort u) {
    return __uint_as_float((unsigned)u << 16);
}
__device__ __forceinline__ float sigmoidf_(float x) {
    return 1.f / (1.f + expf(-x));
}

// async global->LDS, 16B per lane
__device__ __forceinline__ void gload_lds16(const ushort* g, ushort* l) {
    __builtin_amdgcn_global_load_lds(
        (const __attribute__((address_space(1))) unsigned int*)g,
        (__attribute__((address_space(3))) unsigned int*)l, 16, 0, 0);
}

// ---------------------------------------------------------------------------
// Grid barrier: per-block arrival flag lines + 32 fan-out go-lines
// (<=8 pollers per line). No acquire-invalidate: all cross-block mutable
// data is step-unique, producers publish via RELEASE flag stores.
// ---------------------------------------------------------------------------
__device__ __forceinline__ void gbar(unsigned* flags, unsigned* go, unsigned gen) {
    __syncthreads();
    const int tid = threadIdx.x;
    if (blockIdx.x == 0) {
        if (tid >= 1 && tid < NB_) {
            while (__hip_atomic_load(&flags[tid * 32], __ATOMIC_RELAXED,
                                     __HIP_MEMORY_SCOPE_AGENT) < gen)
                __builtin_amdgcn_s_sleep(1);
        }
        __syncthreads();   // all 255 flags observed
        if (tid < 32) {
            // RELEASE publishes block0's phase writes; 32 fan-out lines
            __hip_atomic_store(&go[tid * 32], gen, __ATOMIC_RELEASE,
                               __HIP_MEMORY_SCOPE_AGENT);
        }
    } else {
        if (tid == 0) {
            __hip_atomic_store(&flags[blockIdx.x * 32], gen, __ATOMIC_RELEASE,
                               __HIP_MEMORY_SCOPE_AGENT);
            while (__hip_atomic_load(&go[(blockIdx.x >> 3) * 32], __ATOMIC_RELAXED,
                                     __HIP_MEMORY_SCOPE_AGENT) < gen)
                __builtin_amdgcn_s_sleep(1);
        }
    }
    __syncthreads();
}

// ---------------------------------------------------------------------------
// m97-structure GEMM: C[M,N] = A[M,K] @ W[N,K]^T + bias[N]
// ---------------------------------------------------------------------------
__global__ __launch_bounds__(256) void gemm128_bf16(
    const ushort* __restrict__ A, int lda,
    const ushort* __restrict__ W, int ldw,
    const float* __restrict__ bias,
    float* __restrict__ Cf, ushort* __restrict__ Cb, int ldc,
    int K)
{
    const int bn0 = blockIdx.x * 128;
    const int bm0 = blockIdx.y * 128;
    const int tid = threadIdx.x;
    const int wv  = tid >> 6;
    const int lane = tid & 63;

    __shared__ ushort As[128 * 32];
    __shared__ ushort Bs[128 * 32];

    const int srow = tid >> 2;
    const int scol = (tid & 3) * 8;

    const ushort* gA0 = A + (size_t)(bm0 + srow) * lda + scol;
    const ushort* gA1 = gA0 + (size_t)64 * lda;
    const ushort* gB0 = W + (size_t)(bn0 + srow) * ldw + scol;
    const ushort* gB1 = gB0 + (size_t)64 * ldw;

    ushort* lA0 = &As[tid * 8];
    ushort* lA1 = &As[2048 + tid * 8];
    ushort* lB0 = &Bs[tid * 8];
    ushort* lB1 = &Bs[2048 + tid * 8];

    const int wr0 = (wv >> 1) * 64;
    const int wc0 = (wv & 1) * 64;
    const int frow = lane & 15;
    const int fk   = (lane >> 4) * 8;

    f32x4 acc[4][4];
#pragma unroll
    for (int i = 0; i < 4; ++i)
#pragma unroll
        for (int j = 0; j < 4; ++j) acc[i][j] = (f32x4){0.f, 0.f, 0.f, 0.f};

    for (int k0 = 0; k0 < K; k0 += 32) {
        gload_lds16(gA0 + k0, lA0);
        gload_lds16(gA1 + k0, lA1);
        gload_lds16(gB0 + k0, lB0);
        gload_lds16(gB1 + k0, lB1);
        __syncthreads();

        bf16x8 af[4], bf[4];
#pragma unroll
        for (int rb = 0; rb < 4; ++rb)
            af[rb] = *reinterpret_cast<const bf16x8*>(&As[(wr0 + rb * 16 + frow) * 32 + fk]);
#pragma unroll
        for (int cb = 0; cb < 4; ++cb)
            bf[cb] = *reinterpret_cast<const bf16x8*>(&Bs[(wc0 + cb * 16 + frow) * 32 + fk]);
#pragma unroll
        for (int rb = 0; rb < 4; ++rb)
#pragma unroll
            for (int cb = 0; cb < 4; ++cb)
                acc[rb][cb] = __builtin_amdgcn_mfma_f32_16x16x32_bf16(af[rb], bf[cb], acc[rb][cb], 0, 0, 0);
        __syncthreads();
    }

    const int quad = lane >> 4;
#pragma unroll
    for (int cb = 0; cb < 4; ++cb) {
        const int col = bn0 + wc0 + cb * 16 + frow;
        const float bv = bias ? bias[col] : 0.f;
#pragma unroll
        for (int rb = 0; rb < 4; ++rb) {
            const int row0 = bm0 + wr0 + rb * 16 + quad * 4;
            f32x4 a = acc[rb][cb];
#pragma unroll
            for (int r = 0; r < 4; ++r) {
                const float val = a[r] + bv;
                if (Cb) Cb[(size_t)(row0 + r) * ldc + col] = f2bf(val);
                else    Cf[(size_t)(row0 + r) * ldc + col] = val;
            }
        }
    }
}

// ---------------------------------------------------------------------------
// Packs
// ---------------------------------------------------------------------------
__global__ __launch_bounds__(256) void pack_bf16(
    const float* __restrict__ src, int src_ld, int c0, int ncols,
    ushort* __restrict__ dst, size_t total)
{
    size_t i = (size_t)blockIdx.x * 256 + threadIdx.x;
    const size_t stride = (size_t)gridDim.x * 256;
    for (; i < total; i += stride) {
        size_t r = i / (size_t)ncols;
        int c = (int)(i - r * (size_t)ncols);
        dst[i] = f2bf(src[r * (size_t)src_ld + c0 + c]);
    }
}

__global__ __launch_bounds__(256) void gather_emb(
    const int* __restrict__ target, const float* __restrict__ emb,
    ushort* __restrict__ dst)
{
    const int row = blockIdx.x;          // b*T + t
    const int b = row >> 6;
    const int t = row & 63;
    const int tok = (t == 0) ? 1 : target[b * T_ + t - 1];
    const float* e = emb + (size_t)tok * E_;
    ushort* d = dst + (size_t)row * E_;
    for (int c = threadIdx.x; c < E_; c += 256) d[c] = f2bf(e[c]);
}

__global__ __launch_bounds__(256) void pack_bhq(
    const float* __restrict__ ba, const float* __restrict__ bhh,
    float* __restrict__ dst)
{
    const int j = blockIdx.x * 256 + threadIdx.x;
    if (j < H_) dst[j] = ba[j];
    else if (j < QGH_) dst[j] = bhh[j - H_];
}

// zero flags (256*32) + go (32*32)
__global__ __launch_bounds__(256) void barinit(unsigned* f) {
    const int i = blockIdx.x * 256 + threadIdx.x;
    if (i < 9216) f[i] = 0u;
}

// ---------------------------------------------------------------------------
// Persistent decoder. 256 blocks x 512 threads, 4 flag-barriers per step.
//   P1: qgh (blk = 16-col slice of 4096)
//   P2: scores (blk = b x 32-row s-slice; encp slice LDS-resident)
//   P3: softmax + ctx (blk = b x 512-col e-slice)
//   P4: gi (3 gates) + GRU (blk = 16-j slice x b-quarter)
// qgh/scores/ctx step-unique (no stale-cache hazard without invalidates).
// ---------------------------------------------------------------------------
__global__ __launch_bounds__(512) void decoder_persist(
    const ushort* __restrict__ encp,   // (B,S,H) bf16
    const ushort* __restrict__ enc,    // (B,S,ENC) bf16
    const ushort* __restrict__ ench,   // (B,H) bf16 h0
    const float*  __restrict__ ench_f, // (B,H) fp32 h0
    const ushort* __restrict__ Whq,    // (4096,1024) bf16
    const ushort* __restrict__ Wie,    // (3072,2048) bf16
    const float*  __restrict__ bhq,    // (4096)
    const float*  __restrict__ vvec,   // (1024)
    const float*  __restrict__ giemb,  // (B*T,3H) fp32 (incl b_ih)
    float* __restrict__ qgh_all,       // (T,B,4096) step-unique
    float* __restrict__ scores_all,    // (T,B,S) step-unique
    ushort* __restrict__ ctx_all,      // (T,B,ENC) bf16 step-unique
    float* __restrict__ hall_f,        // (B,T,H)
    ushort* __restrict__ hall_b,       // (B,T,H)
    unsigned* __restrict__ flags,
    unsigned* __restrict__ go)
{
    extern __shared__ __align__(16) char smem[];
    const int blk = blockIdx.x;
    const int tid = threadIdx.x;
    const int wv = tid >> 6;
    const int lane = tid & 63;
    const int frow = lane & 15;
    const int fk = (lane >> 4) * 8;

    const int ab = blk >> 2;           // attention b (P2/P3)
    const int aq = blk & 3;            // quarter index

    // ---- preload this block's encp slice (b=ab, rows aq*32..+32) into LDS ----
    {
        const char* src = (const char*)(encp + ((size_t)ab * S_ + aq * 32) * H_);
#pragma unroll
        for (int r = 0; r < 8; ++r) {
            const int ci = r * 8 + wv;   // 0..63 KB-chunks
            gload_lds16((const ushort*)(src + ci * 1024 + lane * 16),
                        (ushort*)(smem + SMEM_ENCP + ci * 1024 + lane * 16));
        }
    }
    // v fragment: lane owns h in [lane*8,+8) and [512+lane*8,+8)
    float vr[16];
    *reinterpret_cast<f32x4*>(&vr[0])  = *reinterpret_cast<const f32x4*>(vvec + lane * 8);
    *reinterpret_cast<f32x4*>(&vr[4])  = *reinterpret_cast<const f32x4*>(vvec + lane * 8 + 4);
    *reinterpret_cast<f32x4*>(&vr[8])  = *reinterpret_cast<const f32x4*>(vvec + 512 + lane * 8);
    *reinterpret_cast<f32x4*>(&vr[12]) = *reinterpret_cast<const f32x4*>(vvec + 512 + lane * 8 + 4);
    __syncthreads();   // drains the global_load_lds

    unsigned gen = 0;

    for (int t = 0; t < T_; ++t) {
        const ushort* hb = t ? (hall_b + (size_t)(t - 1) * H_) : ench;
        const float*  hf = t ? (hall_f + (size_t)(t - 1) * H_) : ench_f;
        const int ldh = t ? (T_ * H_) : H_;
        float* qgh = qgh_all + (size_t)t * B_ * QGH_;
        float* scores = scores_all + (size_t)t * B_ * S_;
        ushort* ctx = ctx_all + (size_t)t * B_ * ENC_;

        // ---------------- P1: qgh ----------------
        {
            f32x4 (*red)[64] = reinterpret_cast<f32x4(*)[64]>(smem + SMEM_SCR);
            const int n0 = blk * 16;
            const int mt = wv & 3;      // m-tile (16 rows)
            const int kh = wv >> 2;     // K-half
            const ushort* Arow = hb + (size_t)(mt * 16 + frow) * ldh + kh * 512 + fk;
            const ushort* Brow = Whq + (size_t)(n0 + frow) * H_ + kh * 512 + fk;
            f32x4 acc = (f32x4){0.f, 0.f, 0.f, 0.f};
#pragma unroll
            for (int c = 0; c < 16; ++c) {
                bf16x8 a = *reinterpret_cast<const bf16x8*>(Arow + c * 32);
                bf16x8 b = *reinterpret_cast<const bf16x8*>(Brow + c * 32);
                acc = __builtin_amdgcn_mfma_f32_16x16x32_bf16(a, b, acc, 0, 0, 0);
            }
            red[wv][lane] = acc;
            __syncthreads();
            if (wv < 4) {
                f32x4 s = red[wv][lane] + red[wv + 4][lane];
                const int col = n0 + frow;
                const float bv = bhq[col];
                const int row0 = wv * 16 + (lane >> 4) * 4;
#pragma unroll
                for (int r = 0; r < 4; ++r)
                    qgh[(size_t)(row0 + r) * QGH_ + col] = s[r] + bv;
            }
        }
        gbar(flags, go, ++gen);

        // ---------------- P2: scores from LDS encp ----------------
        {
            float qr[16];
            *reinterpret_cast<f32x4*>(&qr[0])  = *reinterpret_cast<const f32x4*>(qgh + (size_t)ab * QGH_ + lane * 8);
            *reinterpret_cast<f32x4*>(&qr[4])  = *reinterpret_cast<const f32x4*>(qgh + (size_t)ab * QGH_ + lane * 8 + 4);
            *reinterpret_cast<f32x4*>(&qr[8])  = *reinterpret_cast<const f32x4*>(qgh + (size_t)ab * QGH_ + 512 + lane * 8);
            *reinterpret_cast<f32x4*>(&qr[12]) = *reinterpret_cast<const f32x4*>(qgh + (size_t)ab * QGH_ + 512 + lane * 8 + 4);
#pragma unroll
            for (int i = 0; i < 4; ++i) {
                const int sl = wv * 4 + i;     // local row 0..31
                const char* rowp = smem + SMEM_ENCP + sl * 2048;
                u16x8 e0 = *reinterpret_cast<const u16x8*>(rowp + lane * 16);
                u16x8 e1 = *reinterpret_cast<const u16x8*>(rowp + 1024 + lane * 16);
                float p = 0.f;
#pragma unroll
                for (int j = 0; j < 8; ++j)
                    p += vr[j] * tanhf(qr[j] + bf2f(e0[j]));
#pragma unroll
                for (int j = 0; j < 8; ++j)
                    p += vr[8 + j] * tanhf(qr[8 + j] + bf2f(e1[j]));
#pragma unroll
                for (int off = 32; off; off >>= 1) p += __shfl_xor(p, off);
                if (lane == 0) scores[ab * S_ + aq * 32 + sl] = p;
            }
        }
        gbar(flags, go, ++gen);

        // ---------------- P3: softmax + ctx (row-wise enc stream) ----------------
        {
            float* part = reinterpret_cast<float*>(smem + SMEM_SCR);      // [8][512]
            float* al   = reinterpret_cast<float*>(smem + SMEM_SCR + 16384); // [128]
            const int e0c = aq * 512;
            if (tid < 64) {
                float a0 = scores[ab * S_ + tid];
                float a1 = scores[ab * S_ + tid + 64];
                float m = fmaxf(a0, a1);
#pragma unroll
                for (int off = 32; off; off >>= 1) m = fmaxf(m, __shfl_xor(m, off));
                float e0v = expf(a0 - m), e1v = expf(a1 - m);
                float ssum = e0v + e1v;
#pragma unroll
                for (int off = 32; off; off >>= 1) ssum += __shfl_xor(ssum, off);
                const float inv = 1.f / ssum;
                al[tid] = e0v * inv;
                al[tid + 64] = e1v * inv;
            }
            __syncthreads();
            // wave wv accumulates rows s = wv, wv+8, ..; lane owns 8 cols
            float acc[8];
#pragma unroll
            for (int j = 0; j < 8; ++j) acc[j] = 0.f;
            const ushort* ebase = enc + (size_t)ab * S_ * ENC_ + e0c + lane * 8;
#pragma unroll 4
            for (int i = 0; i < 16; ++i) {
                const int s = wv + i * 8;
                u16x8 ev = *reinterpret_cast<const u16x8*>(ebase + (size_t)s * ENC_);
                const float a = al[s];
#pragma unroll
                for (int j = 0; j < 8; ++j)
                    acc[j] = fmaf(a, bf2f(ev[j]), acc[j]);
            }
            *reinterpret_cast<f32x4*>(part + wv * 512 + lane * 8)     = *reinterpret_cast<f32x4*>(&acc[0]);
            *reinterpret_cast<f32x4*>(part + wv * 512 + lane * 8 + 4) = *reinterpret_cast<f32x4*>(&acc[4]);
            __syncthreads();
            float scol = part[tid];
#pragma unroll
            for (int w = 1; w < 8; ++w) scol += part[w * 512 + tid];
            ctx[(size_t)ab * ENC_ + e0c + tid] = f2bf(scol);
        }
        gbar(flags, go, ++gen);

        // ---------------- P4: gi (3 gates) + GRU ----------------
        {
            f32x4 (*redp)[3][64] = reinterpret_cast<f32x4(*)[3][64]>(smem + SMEM_SCR);
            float (*gt)[16][16] = reinterpret_cast<float(*)[16][16]>(smem + SMEM_SCR + 24576);
            const int jt = blk >> 2;     // j-slice 0..63
            const int b0 = (blk & 3) * 16;
            const int kc = wv * 256;     // K-chunk per wave

            const ushort* Arow = ctx + (size_t)(b0 + frow) * ENC_ + kc + fk;
            const ushort* Brow = Wie + (size_t)(jt * 16 + frow) * ENC_ + kc + fk;
            f32x4 a0 = (f32x4){0.f, 0.f, 0.f, 0.f};
            f32x4 a1 = a0, a2 = a0;
#pragma unroll
            for (int c = 0; c < 8; ++c) {
                bf16x8 av = *reinterpret_cast<const bf16x8*>(Arow + c * 32);
                bf16x8 br = *reinterpret_cast<const bf16x8*>(Brow + c * 32);
                bf16x8 bz = *reinterpret_cast<const bf16x8*>(Brow + (size_t)1024 * ENC_ + c * 32);
                bf16x8 bn = *reinterpret_cast<const bf16x8*>(Brow + (size_t)2048 * ENC_ + c * 32);
                a0 = __builtin_amdgcn_mfma_f32_16x16x32_bf16(av, br, a0, 0, 0, 0);
                a1 = __builtin_amdgcn_mfma_f32_16x16x32_bf16(av, bz, a1, 0, 0, 0);
                a2 = __builtin_amdgcn_mfma_f32_16x16x32_bf16(av, bn, a2, 0, 0, 0);
            }
            redp[wv][0][lane] = a0;
            redp[wv][1][lane] = a1;
            redp[wv][2][lane] = a2;
            __syncthreads();
            if (wv < 3) {
                f32x4 s = redp[0][wv][lane];
#pragma unroll
                for (int w = 1; w < 8; ++w) s += redp[w][wv][lane];
                const int row0 = (lane >> 4) * 4;
#pragma unroll
                for (int r = 0; r < 4; ++r) gt[wv][row0 + r][frow] = s[r];
            }
            __syncthreads();
            if (tid < 256) {
                const int bl = tid >> 4, jl = tid & 15;
                const int b = b0 + bl;
                const int j = jt * 16 + jl;
                const size_t gr = (size_t)(b * T_ + t) * G3_;
                const float ir  = gt[0][bl][jl] + giemb[gr + j];
                const float iz  = gt[1][bl][jl] + giemb[gr + H_ + j];
                const float in_ = gt[2][bl][jl] + giemb[gr + 2 * H_ + j];
                const float* ghp = qgh + (size_t)b * QGH_ + H_;
                const float r = sigmoidf_(ir + ghp[j]);
                const float z = sigmoidf_(iz + ghp[H_ + j]);
                const float n = tanhf(in_ + r * ghp[2 * H_ + j]);
                const float hnew = (1.f - z) * n + z * hf[(size_t)b * ldh + j];
                const size_t ho = (size_t)b * (T_ * H_) + (size_t)t * H_ + j;
                hall_f[ho] = hnew;
                hall_b[ho] = f2bf(hnew);
            }
        }
        gbar(flags, go, ++gen);
    }
}

// ---------------------------------------------------------------------------
static inline int pgrid(size_t total) {
    size_t nb = (total + 255) / 256;
    if (nb > 4096) nb = 4096;
    return (int)nb;
}

extern "C" void kernel_launch(void* const* d_in, const int* in_sizes, int n_in,
                              void* d_out, int out_size, void* d_ws, size_t ws_size,
                              hipStream_t stream) {
    const float* enc    = (const float*)d_in[0];
    const float* enc_h  = (const float*)d_in[1];
    const int*   target = (const int*)  d_in[2];
    const float* emb    = (const float*)d_in[3];
    const float* Wa     = (const float*)d_in[4];
    const float* ba     = (const float*)d_in[5];
    const float* vvec   = (const float*)d_in[6];
    const float* W_ih   = (const float*)d_in[7];
    const float* b_ih   = (const float*)d_in[8];
    const float* W_hh   = (const float*)d_in[9];
    const float* b_hh   = (const float*)d_in[10];
    const float* Wo     = (const float*)d_in[11];
    const float* bo     = (const float*)d_in[12];
    float* out = (float*)d_out;

    char* p = (char*)d_ws;
    auto alloc_u16 = [&](size_t n) { ushort* r = (ushort*)p; p += n * 2; return r; };
    auto alloc_f32 = [&](size_t n) { float* r = (float*)p; p += n * 4; return r; };

    ushort* enc_bf  = alloc_u16((size_t)B_ * S_ * ENC_);
    ushort* encp_bf = alloc_u16((size_t)B_ * S_ * H_);
    ushort* Wo_bf   = alloc_u16((size_t)V_ * H_);
    ushort* Wae_bf  = alloc_u16((size_t)H_ * ENC_);
    ushort* Whq_bf  = alloc_u16((size_t)QGH_ * H_);
    ushort* Wie_bf  = alloc_u16((size_t)G3_ * ENC_);
    ushort* Wiee_bf = alloc_u16((size_t)G3_ * E_);
    ushort* ench_bf = alloc_u16((size_t)B_ * H_);
    ushort* Xemb_bf = alloc_u16((size_t)B_ * T_ * E_);
    ushort* hall_bf = alloc_u16((size_t)B_ * T_ * H_);
    ushort* ctx_all = alloc_u16((size_t)T_ * B_ * ENC_);   // step-unique
    float* hall_f   = alloc_f32((size_t)B_ * T_ * H_);
    float* giemb    = alloc_f32((size_t)B_ * T_ * G3_);
    float* qgh_all  = alloc_f32((size_t)T_ * B_ * QGH_);   // step-unique
    float* scr_all  = alloc_f32((size_t)T_ * B_ * S_);     // step-unique scores
    float* bhq      = alloc_f32((size_t)QGH_);
    unsigned* flags = (unsigned*)alloc_f32(9472);  // 256*32 flags + 32*32 go
    unsigned* go    = flags + 8192;

    const int LDW = H_ + ENC_;   // 3072

    // ---- packs ----
    pack_bf16<<<pgrid((size_t)B_*S_*ENC_), 256, 0, stream>>>(enc, ENC_, 0, ENC_, enc_bf, (size_t)B_*S_*ENC_);
    pack_bf16<<<pgrid((size_t)V_*H_), 256, 0, stream>>>(Wo, H_, 0, H_, Wo_bf, (size_t)V_*H_);
    pack_bf16<<<pgrid((size_t)H_*ENC_), 256, 0, stream>>>(Wa, LDW, H_, ENC_, Wae_bf, (size_t)H_*ENC_);
    pack_bf16<<<pgrid((size_t)H_*H_), 256, 0, stream>>>(Wa, LDW, 0, H_, Whq_bf, (size_t)H_*H_);
    pack_bf16<<<pgrid((size_t)G3_*H_), 256, 0, stream>>>(W_hh, H_, 0, H_, Whq_bf + (size_t)H_*H_, (size_t)G3_*H_);
    pack_bf16<<<pgrid((size_t)G3_*ENC_), 256, 0, stream>>>(W_ih, XDIM_, E_, ENC_, Wie_bf, (size_t)G3_*ENC_);
    pack_bf16<<<pgrid((size_t)G3_*E_), 256, 0, stream>>>(W_ih, XDIM_, 0, E_, Wiee_bf, (size_t)G3_*E_);
    pack_bf16<<<pgrid((size_t)B_*H_), 256, 0, stream>>>(enc_h, H_, 0, H_, ench_bf, (size_t)B_*H_);
    gather_emb<<<B_*T_, 256, 0, stream>>>(target, emb, Xemb_bf);
    pack_bhq<<<QGH_/256, 256, 0, stream>>>(ba, b_hh, bhq);
    barinit<<<37, 256, 0, stream>>>(flags);

    // ---- big parallel GEMMs ----
    gemm128_bf16<<<dim3(H_/128, (B_*S_)/128), 256, 0, stream>>>(
        enc_bf, ENC_, Wae_bf, ENC_, nullptr, nullptr, encp_bf, H_, ENC_);
    gemm128_bf16<<<dim3(G3_/128, (B_*T_)/128), 256, 0, stream>>>(
        Xemb_bf, E_, Wiee_bf, E_, b_ih, giemb, nullptr, G3_, E_);

    // ---- persistent recurrence (93 KB dynamic LDS) ----
    decoder_persist<<<NB_, 512, SMEM_TOTAL, stream>>>(
        encp_bf, enc_bf, ench_bf, enc_h, Whq_bf, Wie_bf, bhq, vvec, giemb,
        qgh_all, scr_all, ctx_all, hall_f, hall_bf, flags, go);

    // ---- output projection ----
    gemm128_bf16<<<dim3(V_/128, (B_*T_)/128), 256, 0, stream>>>(
        hall_bf, H_, Wo_bf, H_, bo, out, nullptr, V_, H_);
}